// Round 1
// baseline (73.008 us; speedup 1.0000x reference)
//
#include <hip/hip_runtime.h>
#include <stdint.h>
#include <math.h>

// Problem shape (fixed by the reference's setup_inputs).
constexpr int B = 64, T = 128, C = 6625, L = 25;
constexpr int S = 2 * L + 1;   // 51 extended states
constexpr int NCLS = L + 1;    // gathered classes per (b,t): [blank, label0..label24]

#define NEGV (-1e30f)

// ---- online logsumexp helpers ------------------------------------------------
__device__ inline void lse_acc(float& m, float& s, float x) {
    if (x > m) { s = s * __expf(m - x) + 1.0f; m = x; }
    else       { s += __expf(x - m); }
}
__device__ inline void lse_combine(float& m, float& s, float m2, float s2) {
    float M = fmaxf(m, m2);
    s = s * __expf(m - M) + s2 * __expf(m2 - M);
    m = M;
}

// ---- K1: per-(b,t) logsumexp over C, then gather the 26 needed classes -------
// GATHER=true : write lp[row*NCLS + k] = predicts[row,cls_k] - lse   (fast path)
// GATHER=false: write lse[row] only                                  (small-ws path)
template <bool GATHER>
__global__ __launch_bounds__(256) void k_lse_gather(
    const float* __restrict__ predicts, const int* __restrict__ labels,
    float* __restrict__ lse_out, float* __restrict__ lp_out)
{
    const int row = blockIdx.x;          // row = b*T + t
    const int b   = row / T;
    const int tid = threadIdx.x;
    const float* rp = predicts + (size_t)row * C;

    float m = -1e38f, s = 0.0f;

    // head scalars to reach 16B alignment (rows are only 4B aligned: C is odd)
    int head = (int)(((16u - ((uint32_t)(uintptr_t)rp & 15u)) & 15u) >> 2);
    if (head > C) head = C;
    for (int c = tid; c < head; c += 256) lse_acc(m, s, rp[c]);

    const int nvec = (C - head) >> 2;
    const float4* vp = (const float4*)(rp + head);
    for (int i = tid; i < nvec; i += 256) {
        float4 x = vp[i];
        lse_acc(m, s, x.x); lse_acc(m, s, x.y);
        lse_acc(m, s, x.z); lse_acc(m, s, x.w);
    }
    for (int c = head + (nvec << 2) + tid; c < C; c += 256) lse_acc(m, s, rp[c]);

    // wave64 butterfly-style reduce (down-shuffles)
    for (int off = 32; off; off >>= 1) {
        float m2 = __shfl_down(m, off);
        float s2 = __shfl_down(s, off);
        lse_combine(m, s, m2, s2);
    }
    __shared__ float sm[4], ss[4];
    __shared__ float s_lse;
    const int wave = tid >> 6, lane = tid & 63;
    if (lane == 0) { sm[wave] = m; ss[wave] = s; }
    __syncthreads();
    if (tid == 0) {
        float M = sm[0], Sv = ss[0];
        for (int w = 1; w < 4; ++w) lse_combine(M, Sv, sm[w], ss[w]);
        s_lse = M + __logf(Sv);
    }
    __syncthreads();
    const float lse = s_lse;

    if (GATHER) {
        if (tid < NCLS) {
            const int cls = (tid == 0) ? 0 : labels[b * L + tid - 1];
            lp_out[(size_t)row * NCLS + tid] = rp[cls] - lse;   // L1-hot gather
        }
    } else {
        if (tid == 0) lse_out[row] = lse;
    }
}

// ---- K2: CTC alpha recursion, one batch per block, one state per lane --------
template <bool USE_LP>
__global__ __launch_bounds__(64) void k_ctc(
    const float* __restrict__ predicts, const int* __restrict__ labels,
    const int* __restrict__ lens, const float* __restrict__ lse,
    const float* __restrict__ lp_ws, float* __restrict__ loss_out)
{
    const int b = blockIdx.x;
    const int s = threadIdx.x;            // extended-state index (lanes >= S idle-safe)
    const bool valid = (s < S);
    const int  li = s >> 1;
    const bool isLab = (s & 1) && valid;

    const int myLab = isLab ? labels[b * L + li] : 0;
    const bool allow_skip = isLab && (s >= 3) && (myLab != labels[b * L + li - 1]);
    const int  k   = isLab ? (1 + li) : 0;       // index into gathered lp row
    const int  cls = isLab ? myLab : 0;          // class id (slow path)

    auto fetch = [&](int t) -> float {
        const int row = b * T + t;
        if (USE_LP) return lp_ws[(size_t)row * NCLS + k];
        else        return predicts[(size_t)row * C + cls] - lse[row];
    };

    // t = 0
    float lp0 = fetch(0);
    float alpha = (s <= 1) ? lp0 : NEGV;

    for (int t = 1; t < T; ++t) {
        const float lpt = fetch(t);
        float a1 = __shfl_up(alpha, 1);
        float a2 = __shfl_up(alpha, 2);
        if (s < 1) a1 = NEGV;
        if (!allow_skip) a2 = NEGV;   // allow_skip implies s >= 3
        const float mm  = fmaxf(alpha, fmaxf(a1, a2));
        const float sum = __expf(alpha - mm) + __expf(a1 - mm) + __expf(a2 - mm);
        alpha = mm + __logf(sum) + lpt;
    }

    const int len = lens[b];
    const int idx = 2 * len;              // 2..50, < S
    const float aL = __shfl(alpha, idx);
    const float aP = __shfl(alpha, idx - 1);
    if (s == 0) {
        const float mm = fmaxf(aL, aP);
        float loss = -(mm + __logf(__expf(aL - mm) + __expf(aP - mm)));
        if (!(loss < 1e29f)) loss = 0.0f;   // zero_infinity
        loss_out[b] = loss;
    }
}

// ---- K3: mean over B ---------------------------------------------------------
__global__ __launch_bounds__(64) void k_mean(
    const float* __restrict__ loss, float* __restrict__ out, int n)
{
    float v = (threadIdx.x < n) ? loss[threadIdx.x] : 0.0f;
    for (int off = 32; off; off >>= 1) v += __shfl_down(v, off);
    if (threadIdx.x == 0) out[0] = v / (float)n;
}

extern "C" void kernel_launch(void* const* d_in, const int* in_sizes, int n_in,
                              void* d_out, int out_size, void* d_ws, size_t ws_size,
                              hipStream_t stream)
{
    const float* predicts = (const float*)d_in[0];
    const int*   labels   = (const int*)d_in[1];
    const int*   lens     = (const int*)d_in[2];
    float*       out      = (float*)d_out;

    char* ws = (char*)d_ws;
    const size_t lp_bytes   = (size_t)B * T * NCLS * sizeof(float);
    const size_t need_fast  = lp_bytes + B * sizeof(float) + 256;

    if (ws_size >= need_fast) {
        float* lp_ws   = (float*)ws;
        float* loss_ws = (float*)(ws + lp_bytes);
        k_lse_gather<true><<<B * T, 256, 0, stream>>>(predicts, labels, nullptr, lp_ws);
        k_ctc<true><<<B, 64, 0, stream>>>(predicts, labels, lens, nullptr, lp_ws, loss_ws);
        k_mean<<<1, 64, 0, stream>>>(loss_ws, out, B);
    } else {
        float* lse_ws  = (float*)ws;            // B*T floats
        float* loss_ws = lse_ws + B * T;        // B floats
        k_lse_gather<false><<<B * T, 256, 0, stream>>>(predicts, labels, lse_ws, nullptr);
        k_ctc<false><<<B, 64, 0, stream>>>(predicts, labels, lens, lse_ws, nullptr, loss_ws);
        k_mean<<<1, 64, 0, stream>>>(loss_ws, out, B);
    }
}

// Round 2
// 71.208 us; speedup vs baseline: 1.0253x; 1.0253x over previous
//
#include <hip/hip_runtime.h>
#include <stdint.h>
#include <math.h>

// Problem shape (fixed by the reference's setup_inputs).
constexpr int B = 64, T = 128, C = 6625, L = 25;
constexpr int S = 2 * L + 1;   // 51 extended states
constexpr int NCLS = L + 1;    // gathered classes per (b,t): [blank, label0..label24]

#define NEGV  (-1e30f)
#define NEGINF (-1e38f)

// ---- K1: per-(b,t) logsumexp over C (register-resident two-pass), then gather
// GATHER=true : write lp[row*NCLS + k] = predicts[row,cls_k] - lse   (fast path)
// GATHER=false: write lse[row] only                                  (small-ws path)
template <bool GATHER>
__global__ __launch_bounds__(256) void k_lse_gather(
    const float* __restrict__ predicts, const int* __restrict__ labels,
    float* __restrict__ lse_out, float* __restrict__ lp_out)
{
    const int row = blockIdx.x;          // row = b*T + t
    const int b   = row / T;
    const int tid = threadIdx.x;
    const float* rp = predicts + (size_t)row * C;

    // Row is only 4B-aligned (C odd): peel head to 16B alignment, tail after vecs.
    const int mis  = (int)(((uintptr_t)rp >> 2) & 3);  // misalignment in floats
    const int head = (4 - mis) & 3;                    // 0..3
    const int nvec = (C - head) >> 2;                  // full float4s
    const int tail = C - head - (nvec << 2);           // 0..3
    const float4* vp = (const float4*)(rp + head);

    // Load all of this thread's elements into registers (static indices only).
    float4 v[7];
#pragma unroll
    for (int j = 0; j < 7; ++j) {
        const int i = tid + j * 256;
        if (i < nvec) v[j] = vp[i];
        else          v[j] = make_float4(NEGINF, NEGINF, NEGINF, NEGINF);
    }
    // head (rp[0..head-1]) -> threads 0..head-1; tail -> threads 4..4+tail-1
    float sc = NEGINF;
    if (tid < head)                        sc = rp[tid];
    else if (tid >= 4 && tid < 4 + tail)   sc = rp[head + (nvec << 2) + (tid - 4)];

    // Pass 1: branch-free max.
    float m = sc;
#pragma unroll
    for (int j = 0; j < 7; ++j)
        m = fmaxf(m, fmaxf(fmaxf(v[j].x, v[j].y), fmaxf(v[j].z, v[j].w)));

    const int wave = tid >> 6, lane = tid & 63;
    for (int off = 32; off; off >>= 1) m = fmaxf(m, __shfl_down(m, off));
    __shared__ float smax[4], ssum[4];
    if (lane == 0) smax[wave] = m;
    __syncthreads();
    const float M = fmaxf(fmaxf(smax[0], smax[1]), fmaxf(smax[2], smax[3]));

    // Pass 2: independent exps from registers.
    float s = __expf(sc - M);              // masked slots: exp(-1e38 - M) == 0
#pragma unroll
    for (int j = 0; j < 7; ++j) {
        s += __expf(v[j].x - M) + __expf(v[j].y - M)
           + __expf(v[j].z - M) + __expf(v[j].w - M);
    }
    for (int off = 32; off; off >>= 1) s += __shfl_down(s, off);
    if (lane == 0) ssum[wave] = s;
    __syncthreads();
    const float lse = M + __logf(ssum[0] + ssum[1] + ssum[2] + ssum[3]);

    if (GATHER) {
        if (tid < NCLS) {
            const int cls = (tid == 0) ? 0 : labels[b * L + tid - 1];
            lp_out[(size_t)row * NCLS + tid] = rp[cls] - lse;   // L1/L2-hot gather
        }
    } else {
        if (tid == 0) lse_out[row] = lse;
    }
}

// ---- K2: CTC alpha recursion, one batch per block, one state per lane --------
template <bool USE_LP>
__global__ __launch_bounds__(64) void k_ctc(
    const float* __restrict__ predicts, const int* __restrict__ labels,
    const int* __restrict__ lens, const float* __restrict__ lse,
    const float* __restrict__ lp_ws, float* __restrict__ loss_out)
{
    const int b = blockIdx.x;
    const int s = threadIdx.x;            // extended-state index (lanes >= S idle-safe)
    const bool valid = (s < S);
    const int  li = s >> 1;
    const bool isLab = (s & 1) && valid;

    const int myLab = isLab ? labels[b * L + li] : 0;
    const bool allow_skip = isLab && (s >= 3) && (myLab != labels[b * L + li - 1]);
    const int  k   = isLab ? (1 + li) : 0;       // index into gathered lp row
    const int  cls = isLab ? myLab : 0;          // class id (slow path)

    auto fetch = [&](int t) -> float {
        const int row = b * T + t;
        if (USE_LP) return lp_ws[(size_t)row * NCLS + k];
        else        return predicts[(size_t)row * C + cls] - lse[row];
    };

    // t = 0
    float lp0 = fetch(0);
    float alpha = (s <= 1) ? lp0 : NEGV;

    for (int t = 1; t < T; ++t) {
        const float lpt = fetch(t);
        float a1 = __shfl_up(alpha, 1);
        float a2 = __shfl_up(alpha, 2);
        if (s < 1) a1 = NEGV;
        if (!allow_skip) a2 = NEGV;   // allow_skip implies s >= 3
        const float mm  = fmaxf(alpha, fmaxf(a1, a2));
        const float sum = __expf(alpha - mm) + __expf(a1 - mm) + __expf(a2 - mm);
        alpha = mm + __logf(sum) + lpt;
    }

    const int len = lens[b];
    const int idx = 2 * len;              // 2..50, < S
    const float aL = __shfl(alpha, idx);
    const float aP = __shfl(alpha, idx - 1);
    if (s == 0) {
        const float mm = fmaxf(aL, aP);
        float loss = -(mm + __logf(__expf(aL - mm) + __expf(aP - mm)));
        if (!(loss < 1e29f)) loss = 0.0f;   // zero_infinity
        loss_out[b] = loss;
    }
}

// ---- K3: mean over B ---------------------------------------------------------
__global__ __launch_bounds__(64) void k_mean(
    const float* __restrict__ loss, float* __restrict__ out, int n)
{
    float v = (threadIdx.x < n) ? loss[threadIdx.x] : 0.0f;
    for (int off = 32; off; off >>= 1) v += __shfl_down(v, off);
    if (threadIdx.x == 0) out[0] = v / (float)n;
}

extern "C" void kernel_launch(void* const* d_in, const int* in_sizes, int n_in,
                              void* d_out, int out_size, void* d_ws, size_t ws_size,
                              hipStream_t stream)
{
    const float* predicts = (const float*)d_in[0];
    const int*   labels   = (const int*)d_in[1];
    const int*   lens     = (const int*)d_in[2];
    float*       out      = (float*)d_out;

    char* ws = (char*)d_ws;
    const size_t lp_bytes   = (size_t)B * T * NCLS * sizeof(float);
    const size_t need_fast  = lp_bytes + B * sizeof(float) + 256;

    if (ws_size >= need_fast) {
        float* lp_ws   = (float*)ws;
        float* loss_ws = (float*)(ws + lp_bytes);
        k_lse_gather<true><<<B * T, 256, 0, stream>>>(predicts, labels, nullptr, lp_ws);
        k_ctc<true><<<B, 64, 0, stream>>>(predicts, labels, lens, nullptr, lp_ws, loss_ws);
        k_mean<<<1, 64, 0, stream>>>(loss_ws, out, B);
    } else {
        float* lse_ws  = (float*)ws;            // B*T floats
        float* loss_ws = lse_ws + B * T;        // B floats
        k_lse_gather<false><<<B * T, 256, 0, stream>>>(predicts, labels, lse_ws, nullptr);
        k_ctc<false><<<B, 64, 0, stream>>>(predicts, labels, lens, lse_ws, nullptr, loss_ws);
        k_mean<<<1, 64, 0, stream>>>(loss_ws, out, B);
    }
}

// Round 3
// 54.741 us; speedup vs baseline: 1.3337x; 1.3008x over previous
//
#include <hip/hip_runtime.h>
#include <stdint.h>
#include <math.h>

// Problem shape (fixed by the reference's setup_inputs).
constexpr int B = 64, T = 128, C = 6625, L = 25;
constexpr int S = 2 * L + 1;   // 51 extended states
constexpr int NCLS = L + 1;    // gathered classes per (b,t): [blank, label0..label24]

#define LOG2E  1.44269504088896340736f
#define LN2    0.69314718055994530942f
#define NEG2   (-1.4426950408889634e30f)   // -1e30 (natural) expressed in log2 domain
#define NEGINF (-1e38f)

// ---- K1: per-(b,t) logsumexp over C (register-resident two-pass), then gather
// GATHER=true : write lp2[row*NCLS + k] = (predicts[row,cls_k] - lse)*log2e
// GATHER=false: write lse[row] only (small-ws path)
// Block 0 additionally zeroes out[0] so K2 can accumulate the mean atomically.
template <bool GATHER>
__global__ __launch_bounds__(256) void k_lse_gather(
    const float* __restrict__ predicts, const int* __restrict__ labels,
    float* __restrict__ lse_out, float* __restrict__ lp_out,
    float* __restrict__ out)
{
    const int row = blockIdx.x;          // row = b*T + t
    const int b   = row / T;
    const int tid = threadIdx.x;
    const float* rp = predicts + (size_t)row * C;

    if (row == 0 && tid == 255) out[0] = 0.0f;   // K2 atomically accumulates later

    // Row is only 4B-aligned (C odd): peel head to 16B alignment, tail after vecs.
    const int mis  = (int)(((uintptr_t)rp >> 2) & 3);  // misalignment in floats
    const int head = (4 - mis) & 3;                    // 0..3
    const int nvec = (C - head) >> 2;                  // full float4s
    const int tail = C - head - (nvec << 2);           // 0..3
    const float4* vp = (const float4*)(rp + head);

    // Load all of this thread's elements into registers (static indices only).
    float4 v[7];
#pragma unroll
    for (int j = 0; j < 7; ++j) {
        const int i = tid + j * 256;
        if (i < nvec) v[j] = vp[i];
        else          v[j] = make_float4(NEGINF, NEGINF, NEGINF, NEGINF);
    }
    // head (rp[0..head-1]) -> threads 0..head-1; tail -> threads 4..4+tail-1
    float sc = NEGINF;
    if (tid < head)                        sc = rp[tid];
    else if (tid >= 4 && tid < 4 + tail)   sc = rp[head + (nvec << 2) + (tid - 4)];

    // Pass 1: branch-free max.
    float m = sc;
#pragma unroll
    for (int j = 0; j < 7; ++j)
        m = fmaxf(m, fmaxf(fmaxf(v[j].x, v[j].y), fmaxf(v[j].z, v[j].w)));

    const int wave = tid >> 6, lane = tid & 63;
    for (int off = 32; off; off >>= 1) m = fmaxf(m, __shfl_down(m, off));
    __shared__ float smax[4], ssum[4];
    if (lane == 0) smax[wave] = m;
    __syncthreads();
    const float M = fmaxf(fmaxf(smax[0], smax[1]), fmaxf(smax[2], smax[3]));

    // Pass 2: independent exps from registers.
    float s = __expf(sc - M);              // masked slots: exp(-1e38 - M) == 0
#pragma unroll
    for (int j = 0; j < 7; ++j) {
        s += __expf(v[j].x - M) + __expf(v[j].y - M)
           + __expf(v[j].z - M) + __expf(v[j].w - M);
    }
    for (int off = 32; off; off >>= 1) s += __shfl_down(s, off);
    if (lane == 0) ssum[wave] = s;
    __syncthreads();
    const float lse = M + __logf(ssum[0] + ssum[1] + ssum[2] + ssum[3]);

    if (GATHER) {
        if (tid < NCLS) {
            const int cls = (tid == 0) ? 0 : labels[b * L + tid - 1];
            lp_out[(size_t)row * NCLS + tid] = (rp[cls] - lse) * LOG2E; // L2-hot gather
        }
    } else {
        if (tid == 0) lse_out[row] = lse;
    }
}

// ---- K2: CTC alpha recursion, one batch per block (1 wave), state per lane ---
// Entire recursion runs in the log2 domain (exp2/log2 are native v_exp/v_log).
// lp values are double-buffered in registers (16-step chunks, static indices).
template <bool USE_LP>
__global__ __launch_bounds__(64) void k_ctc(
    const float* __restrict__ predicts, const int* __restrict__ labels,
    const int* __restrict__ lens, const float* __restrict__ lse,
    const float* __restrict__ lp_ws, float* __restrict__ out)
{
    const int b = blockIdx.x;
    const int s = threadIdx.x;            // extended-state index (lanes >= S idle-safe)
    const int  li = s >> 1;
    const bool isLab = (s & 1) && (s < S);

    const int myLab = isLab ? labels[b * L + li] : 0;
    const bool allow_skip = isLab && (s >= 3) && (myLab != labels[b * L + li - 1]);
    const int  k   = isLab ? (1 + li) : 0;       // index into gathered lp row
    const int  cls = isLab ? myLab : 0;          // class id (slow path)

    auto fetch = [&](int t) -> float {
        const int row = b * T + t;
        if (USE_LP) return lp_ws[(size_t)row * NCLS + k];
        else        return (predicts[(size_t)row * C + cls] - lse[row]) * LOG2E;
    };

    auto step = [&](float& alpha, float lp2) {
        float a1 = __shfl_up(alpha, 1);
        float a2 = __shfl_up(alpha, 2);
        if (s < 1) a1 = NEG2;
        if (!allow_skip) a2 = NEG2;   // allow_skip implies s >= 3
        const float mm  = fmaxf(alpha, fmaxf(a1, a2));
        const float sum = exp2f(alpha - mm) + exp2f(a1 - mm) + exp2f(a2 - mm);
        alpha = mm + log2f(sum) + lp2;
    };

    constexpr int CH = 16;
    float Av[CH], Bv[CH];
#pragma unroll
    for (int i = 0; i < CH; ++i) Av[i] = fetch(i);

    float alpha = (s <= 1) ? Av[0] : NEG2;

#pragma unroll
    for (int t0 = 0; t0 < T; t0 += 2 * CH) {
        // prefetch next chunk (t0+CH .. t0+2CH-1) while consuming Av
#pragma unroll
        for (int i = 0; i < CH; ++i) { const int tt = t0 + CH + i; Bv[i] = (tt < T) ? fetch(tt) : 0.0f; }
#pragma unroll
        for (int i = 0; i < CH; ++i) { if (t0 == 0 && i == 0) continue; step(alpha, Av[i]); }
        // prefetch chunk after next (t0+2CH ..) while consuming Bv
#pragma unroll
        for (int i = 0; i < CH; ++i) { const int tt = t0 + 2 * CH + i; Av[i] = (tt < T) ? fetch(tt) : 0.0f; }
#pragma unroll
        for (int i = 0; i < CH; ++i) step(alpha, Bv[i]);
    }

    const int len = lens[b];
    const int idx = 2 * len;              // 2..50, < S
    const float aL = __shfl(alpha, idx);
    const float aP = __shfl(alpha, idx - 1);
    if (s == 0) {
        const float mm = fmaxf(aL, aP);
        float loss = -(mm + log2f(exp2f(aL - mm) + exp2f(aP - mm))) * LN2;
        if (!(loss < 1e29f)) loss = 0.0f;   // zero_infinity
        atomicAdd(out, loss * (1.0f / (float)B));
    }
}

extern "C" void kernel_launch(void* const* d_in, const int* in_sizes, int n_in,
                              void* d_out, int out_size, void* d_ws, size_t ws_size,
                              hipStream_t stream)
{
    const float* predicts = (const float*)d_in[0];
    const int*   labels   = (const int*)d_in[1];
    const int*   lens     = (const int*)d_in[2];
    float*       out      = (float*)d_out;

    char* ws = (char*)d_ws;
    const size_t lp_bytes = (size_t)B * T * NCLS * sizeof(float);

    if (ws_size >= lp_bytes) {
        float* lp_ws = (float*)ws;
        k_lse_gather<true><<<B * T, 256, 0, stream>>>(predicts, labels, nullptr, lp_ws, out);
        k_ctc<true><<<B, 64, 0, stream>>>(predicts, labels, lens, nullptr, lp_ws, out);
    } else {
        float* lse_ws = (float*)ws;            // B*T floats
        k_lse_gather<false><<<B * T, 256, 0, stream>>>(predicts, labels, lse_ws, nullptr, out);
        k_ctc<false><<<B, 64, 0, stream>>>(predicts, labels, lens, lse_ws, nullptr, out);
    }
}